// Round 2
// baseline (1906.588 us; speedup 1.0000x reference)
//
#include <hip/hip_runtime.h>
#include <math.h>

#define T_LEN 51200
#define BATCH 1024
#define HDIM 128
#define NIT 100000

typedef __attribute__((ext_vector_type(8))) short short8;
typedef __attribute__((ext_vector_type(16))) float floatx16;

__device__ __forceinline__ unsigned short f2bf(float x) {
    unsigned u = __float_as_uint(x);
    u += 0x7fff + ((u >> 16) & 1);   // RNE
    return (unsigned short)(u >> 16);
}

__device__ __forceinline__ int lower_bound_i(const int* __restrict__ a, int n, int v) {
    int lo = 0, hi = n;
    while (lo < hi) { int m = (lo + hi) >> 1; if (a[m] < v) lo = m + 1; else hi = m; }
    return lo;
}

// One block per batch row; 128 threads = one per feature. Writes bf16 user.
__global__ __launch_bounds__(128) void pool_kernel(
    const int* __restrict__ item_idx, const int* __restrict__ item_seg,
    const int* __restrict__ ent_idx,  const int* __restrict__ ent_seg,
    const int* __restrict__ word_idx, const int* __restrict__ word_seg,
    const float* __restrict__ item_tab, const float* __restrict__ ent_tab,
    const float* __restrict__ word_tab,
    unsigned short* __restrict__ userb, float* __restrict__ sums, float* __restrict__ sums2)
{
    const int b = blockIdx.x;
    const int h = threadIdx.x;
    const int* idxs[3] = {item_idx, ent_idx, word_idx};
    const int* segs[3] = {item_seg, ent_seg, word_seg};
    const float* tabs[3] = {item_tab, ent_tab, word_tab};
    float acc = 0.f;
    #pragma unroll
    for (int tb = 0; tb < 3; ++tb) {
        const int* idx = idxs[tb];
        const float* tab = tabs[tb];
        int lo = lower_bound_i(segs[tb], T_LEN, b);
        int hi = lower_bound_i(segs[tb], T_LEN, b + 1);
        float s0 = 0.f, s1 = 0.f, s2 = 0.f, s3 = 0.f;
        int t = lo;
        for (; t + 3 < hi; t += 4) {
            int i0 = idx[t], i1 = idx[t + 1], i2 = idx[t + 2], i3 = idx[t + 3];
            s0 += tab[(size_t)i0 * HDIM + h];
            s1 += tab[(size_t)i1 * HDIM + h];
            s2 += tab[(size_t)i2 * HDIM + h];
            s3 += tab[(size_t)i3 * HDIM + h];
        }
        for (; t < hi; ++t) s0 += tab[(size_t)idx[t] * HDIM + h];
        float s = (s0 + s1) + (s2 + s3);
        if (hi > lo) acc += s / (float)(hi - lo);
    }
    userb[b * HDIM + h] = f2bf(acc * (1.f / 3.f));
    if (h == 0) { sums[b] = 0.f; sums2[b] = 0.f; }
}

// Block: 256 thr = 4 waves. Block tile: 128 cols (all 1024 rows, 8 chunks of 128).
// Wave tile: 64 rows x 64 cols via 4x mfma_f32_32x32x16_bf16 per k-step.
// B (w stripe) staged LDS once -> regs for whole block. A (user) streamed via LDS.
// PASS 1: sums[row] += sum exp(lin). PASS 2: probs = exp(lin)/sums, sums2 += sum exp(probs).
#define PA 136   // A lds pitch (bf16 elems), 272 B rows, 16B-aligned frag reads
#define PB 132   // B lds pitch
template<int PASS>
__global__ __launch_bounds__(256) void gemm_pass(
    const unsigned short* __restrict__ userb, const float* __restrict__ w,
    const float* __restrict__ bias, float* __restrict__ sums,
    float* __restrict__ sums2, float* __restrict__ probs)
{
    __shared__ unsigned short sbuf[128 * PA];   // 34816 B, reused B-stage then A-chunks
    __shared__ float rinvL[128];

    const int tid = threadIdx.x;
    const int lane = tid & 63;
    const int ln = lane & 31;
    const int q = lane >> 5;
    const int wv = tid >> 6;
    const int m_half = wv & 1;
    const int n_half = wv >> 1;
    const int n0 = blockIdx.x * 128;

    // ---- stage w stripe f32->bf16 into LDS [k][n], pitch PB ----
    for (int i = tid; i < 128 * 32; i += 256) {      // 128 k-rows x 32 float4
        int k = i >> 5, c4 = i & 31;
        int col = n0 + c4 * 4;
        float4 wv4 = make_float4(0.f, 0.f, 0.f, 0.f);
        if (col < NIT) wv4 = *(const float4*)(w + (size_t)k * NIT + col);
        ushort4 hb;
        hb.x = f2bf(wv4.x); hb.y = f2bf(wv4.y); hb.z = f2bf(wv4.z); hb.w = f2bf(wv4.w);
        *(ushort4*)(sbuf + k * PB + c4 * 4) = hb;
    }
    __syncthreads();

    // ---- gather B fragments into registers (held for whole block) ----
    short8 bfr[2][8];
    #pragma unroll
    for (int nt = 0; nt < 2; ++nt)
        #pragma unroll
        for (int kt = 0; kt < 8; ++kt) {
            short8 v;
            #pragma unroll
            for (int j = 0; j < 8; ++j)
                v[j] = (short)sbuf[(16 * kt + 8 * q + j) * PB + 64 * n_half + 32 * nt + ln];
            bfr[nt][kt] = v;
        }

    int  coln[2]; float breg[2]; bool vn[2];
    #pragma unroll
    for (int nt = 0; nt < 2; ++nt) {
        coln[nt] = n0 + 64 * n_half + 32 * nt + ln;
        vn[nt] = coln[nt] < NIT;
        breg[nt] = vn[nt] ? bias[coln[nt]] : 0.f;
    }

    const int mrow0 = 64 * m_half + ln;

    for (int ch = 0; ch < 8; ++ch) {
        const int rb = ch * 128;
        __syncthreads();   // protect LDS before overwrite (also covers B-gather)
        for (int i = tid; i < 128 * 16; i += 256) {   // 128 rows x 16 groups of 8 bf16
            int r = i >> 4, g = i & 15;
            uint4 v = *(const uint4*)(userb + (size_t)(rb + r) * HDIM + g * 8);
            *(uint4*)(sbuf + r * PA + g * 8) = v;
        }
        if (PASS == 2 && tid < 128) rinvL[tid] = 1.f / sums[rb + tid];
        __syncthreads();

        floatx16 acc[2][2];
        #pragma unroll
        for (int a = 0; a < 2; ++a)
            #pragma unroll
            for (int b = 0; b < 2; ++b)
                #pragma unroll
                for (int e = 0; e < 16; ++e) acc[a][b][e] = 0.f;

        #pragma unroll
        for (int kt = 0; kt < 8; ++kt) {
            const int ao = 16 * kt + 8 * q;
            short8 a0 = *(const short8*)(sbuf + mrow0 * PA + ao);
            short8 a1 = *(const short8*)(sbuf + (mrow0 + 32) * PA + ao);
            acc[0][0] = __builtin_amdgcn_mfma_f32_32x32x16_bf16(a0, bfr[0][kt], acc[0][0], 0, 0, 0);
            acc[0][1] = __builtin_amdgcn_mfma_f32_32x32x16_bf16(a0, bfr[1][kt], acc[0][1], 0, 0, 0);
            acc[1][0] = __builtin_amdgcn_mfma_f32_32x32x16_bf16(a1, bfr[0][kt], acc[1][0], 0, 0, 0);
            acc[1][1] = __builtin_amdgcn_mfma_f32_32x32x16_bf16(a1, bfr[1][kt], acc[1][1], 0, 0, 0);
        }

        // ---- epilogue: C/D layout col=lane&31, row=(reg&3)+8*(reg>>2)+4*(lane>>5) ----
        #pragma unroll
        for (int mt = 0; mt < 2; ++mt) {
            #pragma unroll
            for (int rg = 0; rg < 16; ++rg) {
                const int rloc = 64 * m_half + 32 * mt + 4 * q + (rg & 3) + 8 * (rg >> 2);
                float e = 0.f;
                float ri = 0.f;
                if (PASS == 2) ri = rinvL[rloc];
                #pragma unroll
                for (int nt = 0; nt < 2; ++nt) {
                    float lin = acc[mt][nt][rg] + breg[nt];
                    if (PASS == 1) {
                        e += vn[nt] ? __expf(lin) : 0.f;
                    } else {
                        float p = __expf(lin) * ri;
                        if (vn[nt]) {
                            probs[(size_t)(rb + rloc) * NIT + coln[nt]] = p;
                            e += __expf(p);
                        }
                    }
                }
                e += __shfl_xor(e, 1); e += __shfl_xor(e, 2); e += __shfl_xor(e, 4);
                e += __shfl_xor(e, 8); e += __shfl_xor(e, 16);
                if (ln == 0) {
                    float* dst = (PASS == 1) ? sums : sums2;
                    atomicAdd(&dst[rb + rloc], e);
                }
            }
        }
    }
}

__global__ __launch_bounds__(256) void loss_kernel(
    const float* __restrict__ probs, const int* __restrict__ labels,
    const float* __restrict__ sums2, float* __restrict__ out)
{
    __shared__ float red[256];
    float t = 0.f;
    for (int b = threadIdx.x; b < BATCH; b += 256) {
        int lab = labels[b];
        float p = probs[(size_t)b * NIT + lab];
        t += p - logf(sums2[b]);
        out[(size_t)BATCH * NIT + b] = (float)lab;
    }
    red[threadIdx.x] = t;
    __syncthreads();
    for (int s = 128; s > 0; s >>= 1) {
        if (threadIdx.x < s) red[threadIdx.x] += red[threadIdx.x + s];
        __syncthreads();
    }
    if (threadIdx.x == 0) out[(size_t)BATCH * NIT + BATCH] = -red[0] / (float)BATCH;
}

extern "C" void kernel_launch(void* const* d_in, const int* in_sizes, int n_in,
                              void* d_out, int out_size, void* d_ws, size_t ws_size,
                              hipStream_t stream)
{
    const int* item_idx = (const int*)d_in[0];
    const int* item_seg = (const int*)d_in[1];
    const int* ent_idx  = (const int*)d_in[2];
    const int* ent_seg  = (const int*)d_in[3];
    const int* word_idx = (const int*)d_in[4];
    const int* word_seg = (const int*)d_in[5];
    const int* labels   = (const int*)d_in[6];
    const float* item_tab = (const float*)d_in[7];
    const float* ent_tab  = (const float*)d_in[8];
    const float* word_tab = (const float*)d_in[9];
    const float* rec_w    = (const float*)d_in[10];
    const float* rec_b    = (const float*)d_in[11];
    float* out = (float*)d_out;

    unsigned short* userb = (unsigned short*)d_ws;                 // 1024*128 bf16 = 256 KB
    float* sums  = (float*)((char*)d_ws + BATCH * HDIM * 2);       // 1024 f32
    float* sums2 = sums + BATCH;                                   // 1024 f32

    pool_kernel<<<BATCH, 128, 0, stream>>>(item_idx, item_seg, ent_idx, ent_seg,
                                           word_idx, word_seg, item_tab, ent_tab,
                                           word_tab, userb, sums, sums2);

    const int nblk = (NIT + 127) / 128;   // 782
    gemm_pass<1><<<nblk, 256, 0, stream>>>(userb, rec_w, rec_b, sums, sums2, out);
    gemm_pass<2><<<nblk, 256, 0, stream>>>(userb, rec_w, rec_b, sums, sums2, out);

    loss_kernel<<<1, 256, 0, stream>>>(out, labels, sums2, out);
}